// Round 10
// baseline (1493.358 us; speedup 1.0000x reference)
//
#include <hip/hip_runtime.h>

#define HN 10

__device__ __forceinline__ float fast_sigmoid(float x) {
    return __builtin_amdgcn_rcpf(1.0f + __expf(-x));
}
__device__ __forceinline__ float fast_tanh(float x) {
    return 2.0f * __builtin_amdgcn_rcpf(1.0f + __expf(-2.0f * x)) - 1.0f;
}

__device__ __forceinline__ float dot10(const float* __restrict__ w, const float* __restrict__ x) {
    float s = 0.0f;
#pragma unroll
    for (int t = 0; t < 10; ++t) s = __builtin_fmaf(w[t], x[t], s);
    return s;
}

// Single kernel: 128 threads/block. Per-thread history lives in an LDS row of 91
// floats (cols 0..9 = initial h, cols s*10..s*10+9 = h after step s, col 90 pad;
// stride 91 -> bank stride 27, coprime with 32 -> 2-way conflict = free).
// Registers hold only h[10] + hn[10] + x[20] transient -> no spill.
// All global writes happen in a final flush, fully contiguous float2.
__global__ __launch_bounds__(128, 2) void Piston_PolicyHelper_gru_v3(
    const float* __restrict__ policy,   // [B,10]
    const float* __restrict__ neigh,    // [B,8,10]
    const float* __restrict__ w_ih,     // [30,10]
    const float* __restrict__ w_hh,     // [30,10]
    const float* __restrict__ b_ih,     // [30]
    const float* __restrict__ b_hh,     // [30]
    float* __restrict__ out,            // [B*10] final, then [B*90] temp
    int B)
{
    __shared__ __align__(16) float sWI[30 * 12];
    __shared__ __align__(16) float sWH[30 * 12];
    __shared__ float sBI[30];
    __shared__ float sBH[30];
    __shared__ float sH[128 * 91];      // per-thread history rows

    const int tid = threadIdx.x;
    for (int i = tid; i < 300; i += 128) {
        int r = i / 10;
        int c = i - r * 10;
        sWI[r * 12 + c] = w_ih[i];
        sWH[r * 12 + c] = w_hh[i];
    }
    if (tid < 30) { sBI[tid] = b_ih[tid]; sBH[tid] = b_hh[tid]; }
    __syncthreads();

    const int b0 = blockIdx.x * 128;
    const int b  = b0 + tid;            // B divisible by 128
    float* myrow = sH + tid * 91;

    float h[10];
    {
        const float2* p = reinterpret_cast<const float2*>(policy + (size_t)b * 10);
#pragma unroll
        for (int i = 0; i < 5; ++i) {
            float2 v = p[i];
            h[2 * i]     = v.x;
            h[2 * i + 1] = v.y;
        }
    }
    // initial h -> cols 0..9
#pragma unroll
    for (int j = 0; j < 10; ++j) myrow[j] = h[j];

    const float4* nb4 = reinterpret_cast<const float4*>(neigh + (size_t)b * 80);

#pragma unroll
    for (int kk = 0; kk < 4; ++kk) {
        float x[20];
#pragma unroll
        for (int i = 0; i < 5; ++i) {
            float4 v = nb4[kk * 5 + i];
            x[4 * i + 0] = v.x;
            x[4 * i + 1] = v.y;
            x[4 * i + 2] = v.z;
            x[4 * i + 3] = v.w;
        }
#pragma unroll
        for (int s = 0; s < 2; ++s) {
            const int step = kk * 2 + s + 1;     // 1..8, compile-time in unrolled loop
            const float* xs = x + s * 10;
            float hn[10];
#pragma unroll
            for (int j = 0; j < 10; ++j) {
                float ir = sBI[j]      + dot10(sWI + j * 12,        xs);
                float iz = sBI[10 + j] + dot10(sWI + (10 + j) * 12, xs);
                float in = sBI[20 + j] + dot10(sWI + (20 + j) * 12, xs);
                float hr = sBH[j]      + dot10(sWH + j * 12,        h);
                float hz = sBH[10 + j] + dot10(sWH + (10 + j) * 12, h);
                float hg = sBH[20 + j] + dot10(sWH + (20 + j) * 12, h);
                float r = fast_sigmoid(ir + hr);
                float z = fast_sigmoid(iz + hz);
                float n = fast_tanh(in + r * hg);
                hn[j] = (1.0f - z) * n + z * h[j];
            }
#pragma unroll
            for (int j = 0; j < 10; ++j) {
                h[j] = hn[j];
                myrow[step * 10 + j] = hn[j];    // const offset per unrolled step
            }
        }
    }

    __syncthreads();

    // ---- flush temp history: 128 rows x 90 floats = 5760 float2, globally contiguous ----
    // temp float2 index for (row, col2): (b0+row)*45 + col2 = b0*45 + i  (i = row*45+col2)
    {
        float2* dst = reinterpret_cast<float2*>(out + (size_t)B * 10 + (size_t)b0 * 90);
#pragma unroll
        for (int k = 0; k < 45; ++k) {
            int i   = k * 128 + tid;
            int row = i / 45;
            int c   = (i - row * 45) * 2;
            dst[i] = make_float2(sH[row * 91 + c], sH[row * 91 + c + 1]);
        }
    }
    // ---- flush final h (cols 80..89): 128 rows x 5 float2 = 640 float2, contiguous ----
    {
        float2* dst = reinterpret_cast<float2*>(out + (size_t)b0 * 10);
#pragma unroll
        for (int k = 0; k < 5; ++k) {
            int i   = k * 128 + tid;
            int row = i / 5;
            int c   = 80 + (i - row * 5) * 2;
            dst[i] = make_float2(sH[row * 91 + c], sH[row * 91 + c + 1]);
        }
    }
}

extern "C" void kernel_launch(void* const* d_in, const int* in_sizes, int n_in,
                              void* d_out, int out_size, void* d_ws, size_t ws_size,
                              hipStream_t stream) {
    const float* policy = (const float*)d_in[0];
    const float* neigh  = (const float*)d_in[1];
    const float* w_ih   = (const float*)d_in[2];
    const float* w_hh   = (const float*)d_in[3];
    const float* b_ih   = (const float*)d_in[4];
    const float* b_hh   = (const float*)d_in[5];
    float* out = (float*)d_out;

    const int B = in_sizes[0] / HN;   // 262144
    const int grid = B / 128;

    Piston_PolicyHelper_gru_v3<<<grid, 128, 0, stream>>>(
        policy, neigh, w_ih, w_hh, b_ih, b_hh, out, B);
}

// Round 13
// 1214.300 us; speedup vs baseline: 1.2298x; 1.2298x over previous
//
#include <hip/hip_runtime.h>

#define HN 10

__device__ __forceinline__ float fast_sigmoid(float x) {
    return __builtin_amdgcn_rcpf(1.0f + __expf(-x));
}
__device__ __forceinline__ float fast_tanh(float x) {
    return 2.0f * __builtin_amdgcn_rcpf(1.0f + __expf(-2.0f * x)) - 1.0f;
}

__device__ __forceinline__ float dot10(const float* __restrict__ w, const float* __restrict__ x) {
    float s = 0.0f;
#pragma unroll
    for (int t = 0; t < 10; ++t) s = __builtin_fmaf(w[t], x[t], s);
    return s;
}

// ============ Kernel 1: GRU recurrence, history streamed transposed to ws ============
// ws layout: [90][B]. Per-step x loaded just-in-time as 5x float2 (10 floats) so peak
// live regs ~= h[10]+x[10]+hn[10]+addr -> no spill. Every ws store: 64 lanes x 4B
// contiguous (256B, line-aligned since b0 % 64 == 0), each line written exactly once.
__global__ __launch_bounds__(256, 4) void Piston_PolicyHelper_gru_fwd(
    const float* __restrict__ policy,   // [B,10]
    const float* __restrict__ neigh,    // [B,8,10]
    const float* __restrict__ w_ih,     // [30,10]
    const float* __restrict__ w_hh,     // [30,10]
    const float* __restrict__ b_ih,     // [30]
    const float* __restrict__ b_hh,     // [30]
    float* __restrict__ ws,             // [90,B]
    int B)
{
    __shared__ __align__(16) float sWI[30 * 12];
    __shared__ __align__(16) float sWH[30 * 12];
    __shared__ float sBI[30];
    __shared__ float sBH[30];

    const int tid = threadIdx.x;
    for (int i = tid; i < 300; i += 256) {
        int r = i / 10;
        int c = i - r * 10;
        sWI[r * 12 + c] = w_ih[i];
        sWH[r * 12 + c] = w_hh[i];
    }
    if (tid < 30) { sBI[tid] = b_ih[tid]; sBH[tid] = b_hh[tid]; }
    __syncthreads();

    const int b = blockIdx.x * 256 + tid;

    float h[10];
    {
        const float2* p = reinterpret_cast<const float2*>(policy + (size_t)b * 10);
#pragma unroll
        for (int i = 0; i < 5; ++i) {
            float2 v = p[i];
            h[2 * i]     = v.x;
            h[2 * i + 1] = v.y;
        }
    }

    // initial h -> ws rows 0..9
#pragma unroll
    for (int j = 0; j < 10; ++j) ws[(size_t)j * B + b] = h[j];

    const float2* nb2 = reinterpret_cast<const float2*>(neigh + (size_t)b * 80);

#pragma unroll
    for (int step = 0; step < 8; ++step) {
        // load this step's neighbor (10 floats) just-in-time: 5x float2, 8B-aligned
        float x[10];
#pragma unroll
        for (int i = 0; i < 5; ++i) {
            float2 v = nb2[step * 5 + i];   // compile-time offset after unroll
            x[2 * i]     = v.x;
            x[2 * i + 1] = v.y;
        }
        float hn[10];
#pragma unroll
        for (int j = 0; j < 10; ++j) {
            float ir = sBI[j]      + dot10(sWI + j * 12,        x);
            float iz = sBI[10 + j] + dot10(sWI + (10 + j) * 12, x);
            float in = sBI[20 + j] + dot10(sWI + (20 + j) * 12, x);
            float hr = sBH[j]      + dot10(sWH + j * 12,        h);
            float hz = sBH[10 + j] + dot10(sWH + (10 + j) * 12, h);
            float hg = sBH[20 + j] + dot10(sWH + (20 + j) * 12, h);
            float r = fast_sigmoid(ir + hr);
            float z = fast_sigmoid(iz + hz);
            float n = fast_tanh(in + r * hg);
            hn[j] = (1.0f - z) * n + z * h[j];
        }
        const size_t rowBase = (size_t)((step + 1) * 10) * B + b;
#pragma unroll
        for (int j = 0; j < 10; ++j) {
            h[j] = hn[j];
            ws[rowBase + (size_t)j * B] = hn[j];
        }
    }
}

// ============ Kernel 2: transpose ws [90][B] -> out {[B,10] final, [B,9,10] temp} ============
__global__ __launch_bounds__(256, 4) void Piston_PolicyHelper_gru_tr(
    const float* __restrict__ ws,
    float* __restrict__ out,
    int B)
{
    __shared__ float sT[90 * 65];   // [row 90][col 64 +1 pad]

    const int tid = threadIdx.x;
    const int bbase = blockIdx.x * 64;

    // stage: float4 reads along b (64 cols = 16 float4 per row)
    for (int i = tid; i < 1440; i += 256) {
        int row = i >> 4;
        int c4  = i & 15;
        float4 v = *reinterpret_cast<const float4*>(ws + (size_t)row * B + bbase + c4 * 4);
        float* dstRow = sT + row * 65 + c4 * 4;
        dstRow[0] = v.x; dstRow[1] = v.y; dstRow[2] = v.z; dstRow[3] = v.w;
    }
    __syncthreads();

    // temp history: out[B*10 + (bbase+r)*90 + c] = sT[c][r]  (float2 contiguous)
    {
        float2* dst = reinterpret_cast<float2*>(out + (size_t)B * 10 + (size_t)bbase * 90);
        for (int i = tid; i < 2880; i += 256) {
            int e = 2 * i;
            int r = e / 90;
            int c = e - r * 90;
            dst[i] = make_float2(sT[c * 65 + r], sT[(c + 1) * 65 + r]);
        }
    }
    // final h: rows 80..89, scalar contiguous
    for (int i = tid; i < 640; i += 256) {
        int r = i / 10;
        int c = i - r * 10;
        out[(size_t)(bbase + r) * 10 + c] = sT[(80 + c) * 65 + r];
    }
}

// ============ Fallback (verified R1 kernel) if ws too small ============
__global__ __launch_bounds__(256, 3) void Piston_PolicyHelper_gru_mono(
    const float* __restrict__ policy, const float* __restrict__ neigh,
    const float* __restrict__ w_ih, const float* __restrict__ w_hh,
    const float* __restrict__ b_ih, const float* __restrict__ b_hh,
    float* __restrict__ out, int B)
{
    __shared__ __align__(16) float sWI[30 * 12];
    __shared__ __align__(16) float sWH[30 * 12];
    __shared__ float sBI[30];
    __shared__ float sBH[30];
    __shared__ float sBuf[64 * 91];

    const int tid = threadIdx.x;
    for (int i = tid; i < 300; i += 256) {
        int r = i / 10;
        int c = i - r * 10;
        sWI[r * 12 + c] = w_ih[i];
        sWH[r * 12 + c] = w_hh[i];
    }
    if (tid < 30) { sBI[tid] = b_ih[tid]; sBH[tid] = b_hh[tid]; }
    __syncthreads();

    const int b = blockIdx.x * 256 + tid;
    float hist[90];
    {
        const float2* p = reinterpret_cast<const float2*>(policy + (size_t)b * 10);
#pragma unroll
        for (int i = 0; i < 5; ++i) {
            float2 v = p[i];
            hist[2 * i] = v.x;
            hist[2 * i + 1] = v.y;
        }
    }
    const float4* nb4 = reinterpret_cast<const float4*>(neigh + (size_t)b * 80);
#pragma unroll
    for (int kk = 0; kk < 4; ++kk) {
        float x[20];
#pragma unroll
        for (int i = 0; i < 5; ++i) {
            float4 v = nb4[kk * 5 + i];
            x[4 * i + 0] = v.x; x[4 * i + 1] = v.y; x[4 * i + 2] = v.z; x[4 * i + 3] = v.w;
        }
#pragma unroll
        for (int s = 0; s < 2; ++s) {
            const int step = kk * 2 + s;
            const float* xs = x + s * 10;
            const float* hp = hist + step * 10;
            float*       hq = hist + (step + 1) * 10;
#pragma unroll
            for (int j = 0; j < 10; ++j) {
                float ir = sBI[j]      + dot10(sWI + j * 12,        xs);
                float iz = sBI[10 + j] + dot10(sWI + (10 + j) * 12, xs);
                float in = sBI[20 + j] + dot10(sWI + (20 + j) * 12, xs);
                float hr = sBH[j]      + dot10(sWH + j * 12,        hp);
                float hz = sBH[10 + j] + dot10(sWH + (10 + j) * 12, hp);
                float hg = sBH[20 + j] + dot10(sWH + (20 + j) * 12, hp);
                float r = fast_sigmoid(ir + hr);
                float z = fast_sigmoid(iz + hz);
                float n = fast_tanh(in + r * hg);
                hq[j] = (1.0f - z) * n + z * hp[j];
            }
        }
    }
    {
        float2* d = reinterpret_cast<float2*>(out + (size_t)b * 10);
#pragma unroll
        for (int i = 0; i < 5; ++i)
            d[i] = make_float2(hist[80 + 2 * i], hist[80 + 2 * i + 1]);
    }
    const int chunk = tid >> 6;
    const int lane  = tid & 63;
    float* tempBase = out + (size_t)B * 10;
    for (int c = 0; c < 4; ++c) {
        __syncthreads();
        if (chunk == c) {
#pragma unroll
            for (int j = 0; j < 90; ++j) sBuf[lane * 91 + j] = hist[j];
        }
        __syncthreads();
        float2* dst = reinterpret_cast<float2*>(
            tempBase + ((size_t)blockIdx.x * 256 + c * 64) * 90);
        for (int i = tid; i < 2880; i += 256) {
            int e = 2 * i;
            int row = e / 90;
            int col = e - row * 90;
            int w = row * 91 + col;
            dst[i] = make_float2(sBuf[w], sBuf[w + 1]);
        }
    }
}

extern "C" void kernel_launch(void* const* d_in, const int* in_sizes, int n_in,
                              void* d_out, int out_size, void* d_ws, size_t ws_size,
                              hipStream_t stream) {
    const float* policy = (const float*)d_in[0];
    const float* neigh  = (const float*)d_in[1];
    const float* w_ih   = (const float*)d_in[2];
    const float* w_hh   = (const float*)d_in[3];
    const float* b_ih   = (const float*)d_in[4];
    const float* b_hh   = (const float*)d_in[5];
    float* out = (float*)d_out;

    const int B = in_sizes[0] / HN;   // 262144
    const size_t wsNeed = (size_t)B * 90 * sizeof(float);

    if (ws_size >= wsNeed) {
        float* ws = (float*)d_ws;
        Piston_PolicyHelper_gru_fwd<<<(B + 255) / 256, 256, 0, stream>>>(
            policy, neigh, w_ih, w_hh, b_ih, b_hh, ws, B);
        Piston_PolicyHelper_gru_tr<<<B / 64, 256, 0, stream>>>(ws, out, B);
    } else {
        Piston_PolicyHelper_gru_mono<<<(B + 255) / 256, 256, 0, stream>>>(
            policy, neigh, w_ih, w_hh, b_ih, b_hh, out, B);
    }
}